// Round 1
// baseline (43.559 us; speedup 1.0000x reference)
//
#include <hip/hip_runtime.h>
#include <cstddef>

#define SLEN 8192
#define CIN  32
#define COUT 8
#define BATCH 128
#define BCHUNK 4

// tanh(x) = 1 - 2/(exp(2x)+1). exp overflow -> inf -> rcp(inf)=0 -> +1; exp underflow -> 0 -> -1.
__device__ __forceinline__ float fast_tanh(float x) {
    float t = __expf(2.0f * x);                       // v_mul + v_exp_f32
    return 1.0f - 2.0f * __builtin_amdgcn_rcpf(t + 1.0f);
}

// Kernel 1: wsum[j,s] = sum_i w1[i,j,s].  float4 over s.
__global__ __launch_bounds__(256) void lc3_wsum(const float* __restrict__ w1,
                                                float* __restrict__ wsum) {
    int idx = blockIdx.x * 256 + threadIdx.x;        // 0 .. CIN*SLEN/4-1
    int j   = idx / (SLEN / 4);
    int s4  = idx % (SLEN / 4);
    float4 acc = make_float4(0.f, 0.f, 0.f, 0.f);
    #pragma unroll
    for (int i = 0; i < CIN; ++i) {
        const float4 v = *reinterpret_cast<const float4*>(
            &w1[(size_t)(i * CIN + j) * SLEN + (size_t)s4 * 4]);
        acc.x += v.x; acc.y += v.y; acc.z += v.z; acc.w += v.w;
    }
    *reinterpret_cast<float4*>(&wsum[(size_t)j * SLEN + (size_t)s4 * 4]) = acc;
}

// Kernel 2: per thread: one s position, BCHUNK batches, all 8 output channels.
__global__ __launch_bounds__(256) void lc3_main(const float* __restrict__ x,
                                                const float* __restrict__ w1,
                                                const float* __restrict__ w2,
                                                const float* __restrict__ bias,
                                                const float* __restrict__ wsum,
                                                float* __restrict__ out,
                                                int have_ws) {
    const int s  = blockIdx.x * 256 + threadIdx.x;
    const int b0 = blockIdx.y * BCHUNK;

    float acc[BCHUNK][COUT];
    #pragma unroll
    for (int k = 0; k < BCHUNK; ++k)
        #pragma unroll
        for (int o = 0; o < COUT; ++o) acc[k][o] = 0.f;

    for (int j = 0; j < CIN; ++j) {
        float wsv;
        if (have_ws) {
            wsv = wsum[j * SLEN + s];
        } else {
            wsv = 0.f;
            #pragma unroll
            for (int i = 0; i < CIN; ++i) wsv += w1[(i * CIN + j) * SLEN + s];
        }
        float h[BCHUNK];
        #pragma unroll
        for (int k = 0; k < BCHUNK; ++k) {
            float xv = x[((b0 + k) * CIN + j) * SLEN + s];
            h[k] = fast_tanh(xv * wsv);
        }
        #pragma unroll
        for (int o = 0; o < COUT; ++o) {
            float wv = w2[(o * CIN + j) * SLEN + s];
            #pragma unroll
            for (int k = 0; k < BCHUNK; ++k)
                acc[k][o] = fmaf(h[k], wv, acc[k][o]);
        }
    }

    #pragma unroll
    for (int o = 0; o < COUT; ++o) {
        float bv = bias[o * SLEN + s];
        #pragma unroll
        for (int k = 0; k < BCHUNK; ++k)
            out[((b0 + k) * COUT + o) * SLEN + s] = fast_tanh(acc[k][o] + bv);
    }
}

extern "C" void kernel_launch(void* const* d_in, const int* in_sizes, int n_in,
                              void* d_out, int out_size, void* d_ws, size_t ws_size,
                              hipStream_t stream) {
    const float* x    = (const float*)d_in[0];
    const float* w1   = (const float*)d_in[1];
    const float* w2   = (const float*)d_in[2];
    const float* bias = (const float*)d_in[3];
    float* out  = (float*)d_out;
    float* wsum = (float*)d_ws;

    const size_t ws_needed = (size_t)CIN * SLEN * sizeof(float);
    const int have_ws = (ws_size >= ws_needed) ? 1 : 0;

    if (have_ws) {
        // CIN*SLEN/4 float4s / 256 threads = 256 blocks
        lc3_wsum<<<dim3(CIN * SLEN / 4 / 256), dim3(256), 0, stream>>>(w1, wsum);
    }

    dim3 grid(SLEN / 256, BATCH / BCHUNK);
    lc3_main<<<grid, dim3(256), 0, stream>>>(x, w1, w2, bias, wsum, out, have_ws);
}